// Round 1
// baseline (301.825 us; speedup 1.0000x reference)
//
#include <hip/hip_runtime.h>
#include <math.h>

// MultiBoxLoss (RetinaNet focal + smooth-L1) fused kernel for MI355X.
//
// Inputs (setup_inputs order):
//   d_in[0] cls_pred [B, C=80, Na] f32
//   d_in[1] reg_pred [B, 4, Na]    f32
//   d_in[2] annots   [B, 32, 5]    f32  (x1,y1,x2,y2,cls; cls==-1 => pad)
//   d_in[3] anchors  [Na, 4]       f32
// Output: d_out[0] scalar f32 loss.
//
// Workspace layout (zeroed each launch via hipMemsetAsync):
//   double cls_sum[8]; double reg_sum[8]; unsigned int num_pos[8];

namespace {

constexpr int C  = 80;
constexpr int MB = 32;

__global__ __launch_bounds__(256) void multibox_main(
    const float* __restrict__ cls_pred,
    const float* __restrict__ reg_pred,
    const float* __restrict__ annots,
    const float* __restrict__ anchors,
    double* __restrict__ cls_sum,
    double* __restrict__ reg_sum,
    unsigned int* __restrict__ num_pos,
    int Na)
{
    const int b   = blockIdx.y;
    const int tid = threadIdx.x;
    const int a   = blockIdx.x * 256 + tid;
    const bool inb = (a < Na);

    __shared__ float sann[MB * 5];
    __shared__ float swred[4][3];

    if (tid < MB * 5) sann[tid] = annots[(size_t)b * (MB * 5) + tid];
    __syncthreads();

    // ---- anchor load (float4, 16B/lane, coalesced) ----
    float ax1 = 0.f, ay1 = 0.f, ax2 = 0.f, ay2 = 0.f;
    if (inb) {
        const float4 av = *reinterpret_cast<const float4*>(anchors + (size_t)a * 4);
        ax1 = av.x; ay1 = av.y; ax2 = av.z; ay2 = av.w;
    }
    // Non-contracted arithmetic: IoU feeds a hard >=0.5 threshold, keep
    // rounding identical to XLA's unfused elementwise ops.
    const float a_area = __fmul_rn(__fsub_rn(ax2, ax1), __fsub_rn(ay2, ay1));

    // ---- IoU max / argmax over 32 boxes (first-max semantics) ----
    float best = -INFINITY;
    int   bj   = 0;
    for (int j = 0; j < MB; ++j) {
        const float bx1 = sann[j * 5 + 0], by1 = sann[j * 5 + 1];
        const float bx2 = sann[j * 5 + 2], by2 = sann[j * 5 + 3];
        const float bcl = sann[j * 5 + 4];
        float v = -1.0f;                       // invalid (padded) box
        if (bcl != -1.0f) {
            const float barea = __fmul_rn(__fsub_rn(bx2, bx1), __fsub_rn(by2, by1));
            const float iw = fmaxf(__fsub_rn(fminf(ax2, bx2), fmaxf(ax1, bx1)), 0.0f);
            const float ih = fmaxf(__fsub_rn(fminf(ay2, by2), fmaxf(ay1, by1)), 0.0f);
            const float inter = __fmul_rn(iw, ih);
            const float uni   = fmaxf(__fsub_rn(__fadd_rn(a_area, barea), inter), 1e-7f);
            v = __fdiv_rn(inter, uni);
        }
        if (v > best) { best = v; bj = j; }    // strict > keeps FIRST max (jnp.argmax)
    }

    // ---- positives: target class + smooth-L1 regression ----
    int   tc     = -1;    // -1 => all-zero one-hot row
    float my_reg = 0.0f;
    int   my_pos = 0;
    if (inb && best >= 0.5f) {
        my_pos = 1;
        const float gx1 = sann[bj * 5 + 0], gy1 = sann[bj * 5 + 1];
        const float gx2 = sann[bj * 5 + 2], gy2 = sann[bj * 5 + 3];
        tc = (int)sann[bj * 5 + 4];
        const float aw  = ax2 - ax1,        ah  = ay2 - ay1;
        const float acx = ax1 + 0.5f * aw,  acy = ay1 + 0.5f * ah;
        const float gwr = gx2 - gx1,        ghr = gy2 - gy1;
        const float gcx = gx1 + 0.5f * gwr, gcy = gy1 + 0.5f * ghr;
        const float gw  = fmaxf(gwr, 1.0f), gh  = fmaxf(ghr, 1.0f);
        float t[4];
        t[0] = ((gcx - acx) / aw) / 0.1f;
        t[1] = ((gcy - acy) / ah) / 0.1f;
        t[2] = __logf(gw / aw) / 0.2f;
        t[3] = __logf(gh / ah) / 0.2f;
        const size_t rb = ((size_t)b * 4) * (size_t)Na + (size_t)a;
        #pragma unroll
        for (int k = 0; k < 4; ++k) {
            const float r = reg_pred[rb + (size_t)k * Na];
            const float d = fabsf(t[k] - r);
            my_reg += (d <= (1.0f / 9.0f)) ? 4.5f * d * d : d - (0.5f / 9.0f);
        }
    }

    // ---- focal classification loss over 80 classes ----
    // target one-hot: t=1 iff c==tc. For t==0: loss = 0.75*p^2*(-log(1-p));
    // for t==1: loss = 0.25*(1-p)^2*(-log(p)). p clamped to [1e-7, 1-1e-7].
    float csum = 0.0f;
    if (inb) {
        const float* cp = cls_pred + ((size_t)b * C) * (size_t)Na + (size_t)a;
        #pragma unroll 4
        for (int c = 0; c < C; ++c) {
            float p = cp[(size_t)c * Na];
            p = fminf(fmaxf(p, 1e-7f), 1.0f - 1e-7f);
            const float om = 1.0f - p;         // exact for p>=0.5 (Sterbenz)
            float l;
            if (c == tc) l = 0.25f * om * om * (-__logf(p));
            else         l = 0.75f * p  * p  * (-__logf(om));
            csum += l;
        }
    }

    // ---- block reduction (wave shuffle -> LDS -> one atomic per block) ----
    float rc = csum, rr = my_reg;
    int   rp = my_pos;
    #pragma unroll
    for (int off = 32; off > 0; off >>= 1) {
        rc += __shfl_down(rc, off);
        rr += __shfl_down(rr, off);
        rp += __shfl_down(rp, off);
    }
    const int w = tid >> 6;
    if ((tid & 63) == 0) { swred[w][0] = rc; swred[w][1] = rr; swred[w][2] = (float)rp; }
    __syncthreads();
    if (tid == 0) {
        float tcl = 0.f, trg = 0.f, tps = 0.f;
        #pragma unroll
        for (int i = 0; i < 4; ++i) { tcl += swred[i][0]; trg += swred[i][1]; tps += swred[i][2]; }
        atomicAdd(&cls_sum[b], (double)tcl);
        atomicAdd(&reg_sum[b], (double)trg);
        const unsigned int up = (unsigned int)(tps + 0.5f);
        if (up) atomicAdd(&num_pos[b], up);
    }
}

__global__ void finalize_kernel(const double* __restrict__ cls_sum,
                                const double* __restrict__ reg_sum,
                                const unsigned int* __restrict__ num_pos,
                                float* __restrict__ out, int B)
{
    if (threadIdx.x == 0 && blockIdx.x == 0) {
        double tot = 0.0;
        for (int b = 0; b < B; ++b) {
            const double np = (double)num_pos[b];
            tot += cls_sum[b] / fmax(np, 1.0);            // cls: /max(num_pos,1)
            if (np > 0.0) tot += reg_sum[b] / (4.0 * np); // reg: 0 if num_pos==0
        }
        out[0] = (float)(tot / (double)B);
    }
}

} // namespace

extern "C" void kernel_launch(void* const* d_in, const int* in_sizes, int n_in,
                              void* d_out, int out_size, void* d_ws, size_t ws_size,
                              hipStream_t stream)
{
    const float* cls_pred = (const float*)d_in[0];
    const float* reg_pred = (const float*)d_in[1];
    const float* annots   = (const float*)d_in[2];
    const float* anchors  = (const float*)d_in[3];
    float* out = (float*)d_out;

    const int Na = in_sizes[3] / 4;            // 76725
    const int B  = in_sizes[2] / (MB * 5);     // 8

    double*       cls_sum = (double*)d_ws;
    double*       reg_sum = cls_sum + B;
    unsigned int* num_pos = (unsigned int*)(reg_sum + B);

    // Workspace is re-poisoned to 0xAA before every timed launch.
    hipMemsetAsync(d_ws, 0, (size_t)(2 * B) * sizeof(double) + (size_t)B * sizeof(unsigned int), stream);

    dim3 grid((Na + 255) / 256, B);
    multibox_main<<<grid, 256, 0, stream>>>(cls_pred, reg_pred, annots, anchors,
                                            cls_sum, reg_sum, num_pos, Na);
    finalize_kernel<<<1, 64, 0, stream>>>(cls_sum, reg_sum, num_pos, out, B);
}

// Round 5
// 294.048 us; speedup vs baseline: 1.0264x; 1.0264x over previous
//
#include <hip/hip_runtime.h>
#include <math.h>

// MultiBoxLoss (RetinaNet focal + smooth-L1), MI355X.
//
// Structure (round 2, resubmitted x3 — broker timed out; never measured):
//  - negsum_kernel: pure streaming reduce of the NEGATIVE focal term over all
//    B*C*Na elements (float4 loads, no per-class branching). Memory-bound.
//  - assign_kernel: per-anchor IoU argmax (cross-mult compare, single exact
//    div for the >=0.5 test), smooth-L1 for positives, and the f64 focal
//    CORRECTION (pos_term - neg_term at the target class) for positives.
//  - finalize_kernel: normalizations + mean.
//
// Workspace: double cls_sum[B]; double reg_sum[B]; unsigned num_pos[B].

namespace {

constexpr int C  = 80;
constexpr int MB = 32;

__device__ __forceinline__ float clampp(float p) {
    // jnp.clip(p, 1e-7, 1.0-1e-7); (float)(1.0-1e-7) == ref's weak-typed scalar
    return __builtin_amdgcn_fmed3f(p, 1e-7f, (float)(1.0 - 1e-7));
}

// ---------------------------------------------------------------------------
// Kernel 1: assignment. 1 anchor/thread, grid (ceil(Na/256), B).
// ---------------------------------------------------------------------------
__global__ __launch_bounds__(256) void assign_kernel(
    const float* __restrict__ cls_pred,
    const float* __restrict__ reg_pred,
    const float* __restrict__ annots,
    const float* __restrict__ anchors,
    double* __restrict__ cls_sum,
    double* __restrict__ reg_sum,
    unsigned int* __restrict__ num_pos,
    int Na)
{
    const int b   = blockIdx.y;
    const int tid = threadIdx.x;
    const int a   = blockIdx.x * 256 + tid;
    const bool inb = (a < Na);

    __shared__ float4 sbox[MB];    // x1,y1,x2,y2 (invalid -> -1e30 => inter==0)
    __shared__ float2 smeta[MB];   // (area, cls)
    __shared__ double swd[4];
    __shared__ float  swf[4];
    __shared__ int    swi[4];

    if (tid < MB) {
        const float* an = annots + ((size_t)b * MB + tid) * 5;
        float x1 = an[0], y1 = an[1], x2 = an[2], y2 = an[3];
        const float cl = an[4];
        if (cl == -1.0f) { x1 = y1 = x2 = y2 = -1e30f; }
        sbox[tid]  = make_float4(x1, y1, x2, y2);
        smeta[tid] = make_float2(__fmul_rn(__fsub_rn(x2, x1), __fsub_rn(y2, y1)), cl);
    }
    __syncthreads();

    float ax1 = 0.f, ay1 = 0.f, ax2 = 0.f, ay2 = 0.f;
    if (inb) {
        const float4 av = *reinterpret_cast<const float4*>(anchors + (size_t)a * 4);
        ax1 = av.x; ay1 = av.y; ax2 = av.z; ay2 = av.w;
    }
    // Exactly-rounded ops everywhere the >=0.5 threshold can see.
    const float a_area = __fmul_rn(__fsub_rn(ax2, ax1), __fsub_rn(ay2, ay1));

    // argmax over boxes by exact-ratio ordering via cross-multiplication.
    // best ratio state: ibest/ubest (init -1/1 == ref's "invalid = -1" fill).
    float ibest = -1.0f, ubest = 1.0f;
    int   jbest = 0;
    #pragma unroll
    for (int j = 0; j < MB; ++j) {
        const float4 bx = sbox[j];
        const float2 bm = smeta[j];
        const float iw    = fmaxf(__fsub_rn(fminf(ax2, bx.z), fmaxf(ax1, bx.x)), 0.0f);
        const float ih    = fmaxf(__fsub_rn(fminf(ay2, bx.w), fmaxf(ay1, bx.y)), 0.0f);
        const float inter = __fmul_rn(iw, ih);
        const float uni   = fmaxf(__fsub_rn(__fadd_rn(a_area, bm.x), inter), 1e-7f);
        if (inter * ubest > ibest * uni) { ibest = inter; ubest = uni; jbest = j; }
    }

    double corr   = 0.0;   // focal correction (pos - neg at target class)
    float  my_reg = 0.0f;
    int    my_pos = 0;
    // One exact division for the threshold — bit-matches the reference's
    // rounded quotient for the selected box.
    if (inb && __fdiv_rn(ibest, ubest) >= 0.5f) {
        my_pos = 1;
        const float4 g  = sbox[jbest];
        const int    tc = (int)smeta[jbest].y;

        const float aw  = ax2 - ax1,          ah  = ay2 - ay1;
        const float acx = ax1 + 0.5f * aw,    acy = ay1 + 0.5f * ah;
        const float gwr = g.z - g.x,          ghr = g.w - g.y;
        const float gcx = g.x + 0.5f * gwr,   gcy = g.y + 0.5f * ghr;
        const float gw  = fmaxf(gwr, 1.0f),   gh  = fmaxf(ghr, 1.0f);
        float t[4];
        t[0] = ((gcx - acx) / aw) / 0.1f;
        t[1] = ((gcy - acy) / ah) / 0.1f;
        t[2] = __logf(gw / aw) / 0.2f;
        t[3] = __logf(gh / ah) / 0.2f;
        const size_t rb = ((size_t)b * 4) * (size_t)Na + (size_t)a;
        #pragma unroll
        for (int k = 0; k < 4; ++k) {
            const float d = fabsf(t[k] - reg_pred[rb + (size_t)k * Na]);
            my_reg += (d <= (1.0f / 9.0f)) ? 4.5f * d * d : d - (0.5f / 9.0f);
        }

        // focal correction at (b, tc, a): + pos_term - neg_term, where
        // neg_term replicates negsum_kernel's per-element arithmetic.
        float p = clampp(cls_pred[((size_t)b * C + tc) * (size_t)Na + (size_t)a]);
        const float om = __fsub_rn(1.0f, p);   // ref's pt for t=0 / (1-pt) for t=1
        const float q  = __fsub_rn(1.0f, om);  // ref's (1-pt) for t=0
        const float Ln = __logf(om);
        const float Lp = __logf(p);
        const float neg = -0.75f * __fmul_rn(__fmul_rn(q, q), Ln);
        const float pos = 0.25f * __fmul_rn(__fmul_rn(om, om), -Lp);
        corr = (double)pos - (double)neg;
    }

    // block reduction: f64 for corr, f32 for reg, int for count
    double rc = corr;
    float  rr = my_reg;
    int    rp = my_pos;
    #pragma unroll
    for (int off = 32; off > 0; off >>= 1) {
        rc += __shfl_down(rc, off);
        rr += __shfl_down(rr, off);
        rp += __shfl_down(rp, off);
    }
    const int w = tid >> 6;
    if ((tid & 63) == 0) { swd[w] = rc; swf[w] = rr; swi[w] = rp; }
    __syncthreads();
    if (tid == 0) {
        double tcorr = 0.0; float treg = 0.f; int tpos = 0;
        #pragma unroll
        for (int i = 0; i < 4; ++i) { tcorr += swd[i]; treg += swf[i]; tpos += swi[i]; }
        if (tcorr != 0.0) atomicAdd(&cls_sum[b], tcorr);
        if (treg  != 0.f) atomicAdd(&reg_sum[b], (double)treg);
        if (tpos)         atomicAdd(&num_pos[b], (unsigned int)tpos);
    }
}

// ---------------------------------------------------------------------------
// Kernel 2: negative focal term over ALL elements. Pure float4 stream.
// grid (GX, B), grid-stride over C*Na/4 float4s of one image.
// ---------------------------------------------------------------------------
__global__ __launch_bounds__(256) void negsum_kernel(
    const float* __restrict__ cls_pred,
    double* __restrict__ cls_sum,
    int Na)
{
    const int b = blockIdx.y;
    const float4* __restrict__ base =
        reinterpret_cast<const float4*>(cls_pred + (size_t)b * C * (size_t)Na);
    const int n4     = (C * Na) >> 2;          // 1,534,500 (divisible: 4 | C*Na)
    const int stride = gridDim.x * 256;

    float a0 = 0.f, a1 = 0.f, a2 = 0.f, a3 = 0.f;
    #pragma unroll 4
    for (int i = blockIdx.x * 256 + threadIdx.x; i < n4; i += stride) {
        const float4 v = base[i];
        {   const float p = clampp(v.x);
            const float om = __fsub_rn(1.0f, p);
            const float q  = __fsub_rn(1.0f, om);
            a0 = fmaf(__fmul_rn(__fmul_rn(q, q), __logf(om)), -0.75f, a0); }
        {   const float p = clampp(v.y);
            const float om = __fsub_rn(1.0f, p);
            const float q  = __fsub_rn(1.0f, om);
            a1 = fmaf(__fmul_rn(__fmul_rn(q, q), __logf(om)), -0.75f, a1); }
        {   const float p = clampp(v.z);
            const float om = __fsub_rn(1.0f, p);
            const float q  = __fsub_rn(1.0f, om);
            a2 = fmaf(__fmul_rn(__fmul_rn(q, q), __logf(om)), -0.75f, a2); }
        {   const float p = clampp(v.w);
            const float om = __fsub_rn(1.0f, p);
            const float q  = __fsub_rn(1.0f, om);
            a3 = fmaf(__fmul_rn(__fmul_rn(q, q), __logf(om)), -0.75f, a3); }
    }
    float csum = (a0 + a1) + (a2 + a3);

    #pragma unroll
    for (int off = 32; off > 0; off >>= 1) csum += __shfl_down(csum, off);
    __shared__ float sw[4];
    const int tid = threadIdx.x;
    const int w = tid >> 6;
    if ((tid & 63) == 0) sw[w] = csum;
    __syncthreads();
    if (tid == 0) {
        const float tot = (sw[0] + sw[1]) + (sw[2] + sw[3]);
        atomicAdd(&cls_sum[b], (double)tot);
    }
}

// ---------------------------------------------------------------------------
__global__ void finalize_kernel(const double* __restrict__ cls_sum,
                                const double* __restrict__ reg_sum,
                                const unsigned int* __restrict__ num_pos,
                                float* __restrict__ out, int B)
{
    if (threadIdx.x == 0 && blockIdx.x == 0) {
        double tot = 0.0;
        for (int b = 0; b < B; ++b) {
            const double np = (double)num_pos[b];
            tot += cls_sum[b] / fmax(np, 1.0);
            if (np > 0.0) tot += reg_sum[b] / (4.0 * np);
        }
        out[0] = (float)(tot / (double)B);
    }
}

} // namespace

extern "C" void kernel_launch(void* const* d_in, const int* in_sizes, int n_in,
                              void* d_out, int out_size, void* d_ws, size_t ws_size,
                              hipStream_t stream)
{
    const float* cls_pred = (const float*)d_in[0];
    const float* reg_pred = (const float*)d_in[1];
    const float* annots   = (const float*)d_in[2];
    const float* anchors  = (const float*)d_in[3];
    float* out = (float*)d_out;

    const int Na = in_sizes[3] / 4;            // 76725
    const int B  = in_sizes[2] / (MB * 5);     // 8

    double*       cls_sum = (double*)d_ws;
    double*       reg_sum = cls_sum + B;
    unsigned int* num_pos = (unsigned int*)(reg_sum + B);

    hipMemsetAsync(d_ws, 0,
                   (size_t)(2 * B) * sizeof(double) + (size_t)B * sizeof(unsigned int),
                   stream);

    dim3 grid1((Na + 255) / 256, B);
    assign_kernel<<<grid1, 256, 0, stream>>>(cls_pred, reg_pred, annots, anchors,
                                             cls_sum, reg_sum, num_pos, Na);

    dim3 grid2(256, B);                        // 2048 blocks, 8 waves/SIMD resident
    negsum_kernel<<<grid2, 256, 0, stream>>>(cls_pred, cls_sum, Na);

    finalize_kernel<<<1, 64, 0, stream>>>(cls_sum, reg_sum, num_pos, out, B);
}